// Round 1
// 1625.210 us; speedup vs baseline: 1.0892x; 1.0892x over previous
//
#include <hip/hip_runtime.h>
#include <hip/hip_bf16.h>
#include <stdint.h>
#include <math.h>

typedef __hip_bfloat16 bf16;
typedef __attribute__((ext_vector_type(4))) float floatx4;
typedef __attribute__((ext_vector_type(8))) __bf16 bf16x8;

typedef __attribute__((address_space(1))) void gvoid_t;
typedef __attribute__((address_space(3))) void lvoid_t;

__device__ __forceinline__ void gl_lds16(const void* g, void* l){
  __builtin_amdgcn_global_load_lds((gvoid_t*)g, (lvoid_t*)l, 16, 0, 0);
}

__device__ __forceinline__ float gelu_f(float v){
  float u = 0.7978845608028654f*(v + 0.044715f*v*v*v);
  float e = __expf(2.0f*u);
  return v*(1.0f - 1.0f/(e+1.0f));
}

// ---------------- GEMM: C[M,N] = A[M,K](bf16) @ BT[N,K](bf16) + bias ----------
// MODE 0: bf16 C = acc+bias
// MODE 1: bf16 C = gelu(acc+bias)
// MODE 3: bf16 C = (acc+bias) * (n0<1152 ? qs : 1)   [QKV with folded q-scale]
// MODE 4: bf16 partial C[s][M][N] = acc + (s==0 ? bias : 0)   [split-K, blockIdx.z = s]
// 2-phase double-buffered prefetch (T3-minimal): stage(next) issued before compute(cur),
// single __syncthreads per K-step (its vmcnt(0)+lgkmcnt(0) drain IS the pipeline wait).
// LDS 32KB/block -> still 4 blocks/CU with launch_bounds(256,4).
template<int MODE>
__global__ __launch_bounds__(256,4)
void gemm_bf16(const bf16* __restrict__ A, const bf16* __restrict__ BT,
               const float* __restrict__ bias, void* __restrict__ C,
               int N, int K, int kc, float qs)
{
  __shared__ bf16 As[2][128*32];
  __shared__ bf16 Bs[2][128*32];
  const int tid  = threadIdx.x;
  const int wave = tid>>6, lane = tid&63;
  const int quad = lane>>4, l16 = lane&15;

  // ---- T1: bijective XCD-chunked swizzle + GROUP_M=8 over the (x,y) grid ----
  // All grids here have (gridDim.x*gridDim.y) % 8 == 0, so chunks align to the
  // 8-XCD round-robin exactly (perf heuristic only; correctness unaffected).
  int bm, bn;
  {
    const int nx = gridDim.x;
    const int nwg = nx * gridDim.y;
    int lid = blockIdx.x + nx*blockIdx.y;
    const int q = nwg >> 3, r = nwg & 7;
    const int xcd = lid & 7, off = lid >> 3;
    lid = (xcd < r ? xcd*(q+1) : r*(q+1) + (xcd - r)*q) + off;
    const int per = nx << 3;            // blocks per 8-row m-group
    const int g   = lid / per;
    const int rem = lid - g*per;
    bm = (g<<3) + (rem & 7);            // m fastest within group
    bn = rem >> 3;
  }
  const int m0 = bm*128, n0 = bn*128;

  const int s  = blockIdx.z;
  const int kb = s*kc;
  const int ke = min(K, kb + kc);
  const int wm = (wave&1)*64, wn = (wave>>1)*64;
  floatx4 acc[4][4] = {};
  const bf16* ag = A  + (size_t)(m0 + wave*32 + (lane>>2))*K + (lane&3)*8;
  const bf16* bg = BT + (size_t)(n0 + wave*32 + (lane>>2))*K + (lane&3)*8;
  const size_t row16 = (size_t)16*K;
  const int woff = wave*1024;

  // prologue: stage first K-tile into buffer 0
  gl_lds16(ag + kb,          As[0] + woff);
  gl_lds16(ag + kb + row16,  As[0] + woff + 512);
  gl_lds16(bg + kb,          Bs[0] + woff);
  gl_lds16(bg + kb + row16,  Bs[0] + woff + 512);

  int cur = 0;
  for (int k0=kb; k0<ke; k0+=32){
    __syncthreads();                    // drains vmcnt(0): buf[cur] ready; prev reads done
    const int kn = k0 + 32;
    if (kn < ke){                       // issue next tile into the other buffer
      bf16* asn = As[cur^1] + woff;
      bf16* bsn = Bs[cur^1] + woff;
      gl_lds16(ag + kn,          asn);
      gl_lds16(ag + kn + row16,  asn + 512);
      gl_lds16(bg + kn,          bsn);
      gl_lds16(bg + kn + row16,  bsn + 512);
    }
    bf16x8 af[4], bfr[4];
#pragma unroll
    for (int i=0;i<4;i++) af[i]  = *(const bf16x8*)(As[cur] + (wm + i*16 + l16)*32 + quad*8);
#pragma unroll
    for (int j=0;j<4;j++) bfr[j] = *(const bf16x8*)(Bs[cur] + (wn + j*16 + l16)*32 + quad*8);
#pragma unroll
    for (int i=0;i<4;i++)
#pragma unroll
      for (int j=0;j<4;j++)
        acc[i][j] = __builtin_amdgcn_mfma_f32_16x16x32_bf16(af[i], bfr[j], acc[i][j], 0,0,0);
    cur ^= 1;
  }
  const float scale = (MODE==3 && n0<1152) ? qs : 1.0f;
#pragma unroll
  for (int i=0;i<4;i++){
    const int gr0 = m0 + wm + i*16 + quad*4;
#pragma unroll
    for (int j=0;j<4;j++){
      const int gc = n0 + wn + j*16 + l16;
      const float bv = (MODE!=4 || s==0) ? bias[gc] : 0.f;
#pragma unroll
      for (int r=0;r<4;r++){
        const int gr = gr0 + r;
        float v = acc[i][j][r] + bv;
        if constexpr (MODE==1) v = gelu_f(v);
        if constexpr (MODE==3) v *= scale;
        if constexpr (MODE==4){
          ((bf16*)C)[((size_t)s*4096 + gr)*N + gc] = __float2bfloat16(v);
        } else {
          ((bf16*)C)[(size_t)gr*N + gc] = __float2bfloat16(v);
        }
      }
    }
  }
}

// ---------------- fused split-K reduce + residual + LayerNorm ----------------
// x = base[(row&bmask)] + sum_s part_bf16[s][row]; optional xw write; out = LN(x)*g+b
template<int OUTF32, int WRITEX>
__global__ __launch_bounds__(256)
void ln_red(const float* __restrict__ base, unsigned bmask,
            const bf16* __restrict__ part, int ks,
            const float* __restrict__ g, const float* __restrict__ b,
            float* __restrict__ xw, void* __restrict__ out)
{
  const int row  = blockIdx.x*4 + (threadIdx.x>>6);
  const int lane = threadIdx.x & 63;
  const float2* br = (const float2*)base + (size_t)(row & bmask)*576;
  float2 v[9];
#pragma unroll
  for (int r=0;r<9;r++) v[r] = br[r*64+lane];
  for (int s=0;s<ks;s++){
    const __hip_bfloat162* pr = (const __hip_bfloat162*)part + ((size_t)s*4096 + row)*576;
#pragma unroll
    for (int r=0;r<9;r++){
      const float2 pv = __bfloat1622float2(pr[r*64+lane]);
      v[r].x += pv.x; v[r].y += pv.y;
    }
  }
  float sm=0.f, ss=0.f;
#pragma unroll
  for (int r=0;r<9;r++){
    sm += v[r].x + v[r].y;
    ss += v[r].x*v[r].x + v[r].y*v[r].y;
  }
#pragma unroll
  for (int m=1;m<64;m<<=1){ sm += __shfl_xor(sm,m,64); ss += __shfl_xor(ss,m,64); }
  const float mean = sm*(1.0f/1152.0f);
  const float rs = rsqrtf(ss*(1.0f/1152.0f) - mean*mean + 1e-6f);
  const float2* gr2 = (const float2*)g;
  const float2* br2 = (const float2*)b;
#pragma unroll
  for (int r=0;r<9;r++){
    const int c = r*64+lane;
    if constexpr (WRITEX) ((float2*)xw)[(size_t)row*576 + c] = v[r];
    const float2 gg = gr2[c], bb = br2[c];
    const float o0 = (v[r].x-mean)*rs*gg.x + bb.x;
    const float o1 = (v[r].y-mean)*rs*gg.y + bb.y;
    if constexpr (OUTF32){
      ((float2*)out)[(size_t)row*576 + c] = make_float2(o0, o1);
    } else {
      __hip_bfloat162 hv;
      hv.x = __float2bfloat16(o0); hv.y = __float2bfloat16(o1);
      ((__hip_bfloat162*)out)[(size_t)row*576 + c] = hv;
    }
  }
}

// ---------------- im2col for 14x14 stride-14 conv: [4096, 608] bf16 ----
__global__ __launch_bounds__(256)
void im2col_kernel(const float* __restrict__ img, bf16* __restrict__ out)
{
  const int idx = blockIdx.x*256 + threadIdx.x;  // 4096*608
  const int kk = idx % 608;
  const int rr = idx / 608;
  float v = 0.f;
  if (kk < 588){
    const int bt = rr >> 10, n = rr & 1023;
    const int py = n >> 5, px = n & 31;
    const int ph = kk / 42;
    const int rem = kk - ph*42;
    const int pw = rem / 3;
    const int c  = rem - pw*3;
    v = img[(((size_t)bt*448 + py*14 + ph)*448 + px*14 + pw)*3 + c];
  }
  out[idx] = __float2bfloat16(v);
}

// ---------------- fp32 [K,N] -> bf16 [Np,Kp] transpose+convert, zero-pad -----------------
__global__ __launch_bounds__(256)
void transpose_cvt(const float* __restrict__ in, bf16* __restrict__ out,
                   int K, int N, int Kp, int Np)
{
  __shared__ float tile[32][33];
  const int nt = blockIdx.x*32, kt = blockIdx.y*32;
  const int r = threadIdx.x>>5, c = threadIdx.x&31;
#pragma unroll
  for (int i=0;i<4;i++){
    const int k = kt + r + i*8, n = nt + c;
    tile[r+i*8][c] = (k<K && n<N) ? in[(size_t)k*N + n] : 0.f;
  }
  __syncthreads();
#pragma unroll
  for (int i=0;i<4;i++){
    const int n = nt + r + i*8, k = kt + c;
    out[(size_t)n*Kp + k] = __float2bfloat16(tile[c][r+i*8]);
  }
}

// ---------------- bias packing + zero-buffer init ---------------
__global__ __launch_bounds__(256)
void pack_biases(const float* __restrict__ bq, const float* __restrict__ bk,
                 const float* __restrict__ bv, const float* __restrict__ b1,
                 int l, float* __restrict__ bqkv, float* __restrict__ b1p,
                 float4* __restrict__ zbuf)
{
  const int i = blockIdx.x*256 + threadIdx.x;
  if (i < 3456){
    float v;
    if (i < 1152)      v = bq[l*1152 + i];
    else if (i < 2304) v = bk[l*1152 + i - 1152];
    else               v = bv[l*1152 + i - 2304];
    bqkv[i] = v;
  }
  if (i < 4352) b1p[i] = (i < 4304) ? b1[l*4304 + i] : 0.f;
  if (i == 0) *zbuf = make_float4(0.f,0.f,0.f,0.f);
}

// -------- v repack transposed: qkv v-cols -> [64 bh][80 dh][1024 n] (pad rows 0) -----
__global__ __launch_bounds__(256)
void transpose_v(const bf16* __restrict__ src, bf16* __restrict__ dst)
{
  __shared__ bf16 tile[128][73];
  const int nc = blockIdx.x, bh = blockIdx.y;
  const int bt = bh>>4, hh = bh&15;
  const bf16* s = src + ((size_t)bt*1024 + nc*128)*3456 + 2304 + hh*72;
  for (int e=threadIdx.x; e<128*72; e+=256){
    const int n = e/72, dh = e - n*72;
    tile[n][dh] = s[(size_t)n*3456 + dh];
  }
  __syncthreads();
  bf16* d = dst + (size_t)bh*80*1024 + nc*128;
  const bf16 z = __float2bfloat16(0.f);
  for (int e=threadIdx.x; e<80*128; e+=256){
    const int dh = e>>7, n = e&127;
    d[(size_t)dh*1024 + n] = (dh<72) ? tile[n][dh] : z;
  }
}

// ---------------- flash attention, swizzled LDS ------
__global__ __launch_bounds__(256,2)
void attn_kernel(const bf16* __restrict__ qkv, const bf16* __restrict__ vb,
                 const float4* __restrict__ zbuf, bf16* __restrict__ outp)
{
  __shared__ bf16 Ks[128*96];   // 24576 B
  __shared__ bf16 Vs[80*128];   // 20480 B
  __shared__ bf16 Ps[64*128];   // 16384 B
  const int tid = threadIdx.x, wave = tid>>6, lane = tid&63;
  const int quad = lane>>4, l16 = lane&15;
  // T1: XCD-chunked swizzle: 1024 blocks -> 128 contiguous per XCD (8 bh each,
  // so each XCD's K/V working set ~2.4MB fits its private L2)
  int lid = blockIdx.x + (blockIdx.y<<4);
  lid = ((lid & 7) << 7) + (lid >> 3);
  const int bh = lid >> 4, q0 = (lid & 15) << 6;
  const int bt = bh>>4, hh = bh&15;
  const bf16* vg = vb + (size_t)bh*80*1024;
  bf16x8 af0{}, af1{}, af2{};
  {
    const bf16* qp = qkv + (size_t)(bt*1024 + q0 + wave*16 + l16)*3456 + hh*72 + quad*8;
    af0 = *(const bf16x8*)(qp);
    af1 = *(const bf16x8*)(qp+32);
    if (quad==0) af2 = *(const bf16x8*)(qp+64);
  }
  float mr[4], lr[4];
#pragma unroll
  for (int r=0;r<4;r++){ mr[r] = -3.0e38f; lr[r] = 0.f; }
  floatx4 oacc[5] = {};
  for (int kc=0;kc<8;kc++){
    __syncthreads();
    {
      const char* kcb = (const char*)(qkv + (size_t)(bt*1024 + kc*128)*3456 + 1152 + hh*72);
#pragma unroll
      for (int i=0;i<6;i++){
        const int u = (wave*6+i)*64 + lane;      // 0..1535
        const int row = u/12;
        const int pp = u - row*12;
        const int c = (pp & 12) | ((pp & 3) ^ (row & 3));
        const void* src = (c<9) ? (const void*)(kcb + (size_t)row*6912 + c*16)
                                : (const void*)zbuf;
        gl_lds16(src, (char*)Ks + (size_t)(wave*6+i)*1024);
      }
#pragma unroll
      for (int i=0;i<5;i++){
        const int u = (wave*5+i)*64 + lane;      // 0..1279
        const int row = u>>4;
        const int pp = u & 15;
        const int c = (pp & 8) | ((pp & 7) ^ (row & 7));
        gl_lds16((const char*)vg + (size_t)row*2048 + kc*256 + c*16,
                 (char*)Vs + (size_t)(wave*5+i)*1024);
      }
    }
    __syncthreads();
    floatx4 sc[8] = {};
    const int ksw = (quad ^ (l16&3))*8;
#pragma unroll
    for (int ct=0;ct<8;ct++){
      const bf16* kr = Ks + (ct*16+l16)*96 + ksw;
      sc[ct] = __builtin_amdgcn_mfma_f32_16x16x32_bf16(af0, *(const bf16x8*)(kr   ), sc[ct],0,0,0);
      sc[ct] = __builtin_amdgcn_mfma_f32_16x16x32_bf16(af1, *(const bf16x8*)(kr+32), sc[ct],0,0,0);
      sc[ct] = __builtin_amdgcn_mfma_f32_16x16x32_bf16(af2, *(const bf16x8*)(kr+64), sc[ct],0,0,0);
    }
    float cm[4];
#pragma unroll
    for (int r=0;r<4;r++){
      cm[r] = sc[0][r];
#pragma unroll
      for (int ct=1;ct<8;ct++) cm[r] = fmaxf(cm[r], sc[ct][r]);
    }
#pragma unroll
    for (int off=1; off<16; off<<=1)
#pragma unroll
      for (int r=0;r<4;r++) cm[r] = fmaxf(cm[r], __shfl_xor(cm[r], off, 64));
    float al[4], ls[4];
#pragma unroll
    for (int r=0;r<4;r++){
      const float mn = fmaxf(mr[r], cm[r]);
      al[r] = exp2f(mr[r]-mn);
      mr[r] = mn; ls[r] = 0.f;
    }
#pragma unroll
    for (int ct=0;ct<8;ct++){
#pragma unroll
      for (int r=0;r<4;r++){
        const float pv = exp2f(sc[ct][r]-mr[r]);
        ls[r] += pv;
        const int row = wave*16+quad*4+r;
        const int c = ct*2 + (l16>>3);
        const int pp = (c & 8) | ((c & 7) ^ (row & 7));
        Ps[row*128 + pp*8 + (l16&7)] = __float2bfloat16(pv);
      }
    }
#pragma unroll
    for (int off=1; off<16; off<<=1)
#pragma unroll
      for (int r=0;r<4;r++) ls[r] += __shfl_xor(ls[r], off, 64);
#pragma unroll
    for (int r=0;r<4;r++) lr[r] = lr[r]*al[r] + ls[r];
#pragma unroll
    for (int t=0;t<5;t++)
#pragma unroll
      for (int r=0;r<4;r++) oacc[t][r] *= al[r];
    __syncthreads();
#pragma unroll
    for (int ks=0;ks<4;ks++){
      const int c = ks*4 + quad;
      const int pp = (c & 8) | ((c & 7) ^ (l16 & 7));
      const bf16x8 pf = *(const bf16x8*)(Ps + (wave*16+l16)*128 + pp*8);
#pragma unroll
      for (int t=0;t<5;t++){
        const bf16x8 vf = *(const bf16x8*)(Vs + (t*16+l16)*128 + pp*8);
        oacc[t] = __builtin_amdgcn_mfma_f32_16x16x32_bf16(pf, vf, oacc[t],0,0,0);
      }
    }
  }
#pragma unroll
  for (int t=0;t<5;t++){
    const int dh = t*16+l16;
    if (dh < 72){
#pragma unroll
      for (int r=0;r<4;r++){
        const int q = wave*16 + quad*4 + r;
        const float v = oacc[t][r] / lr[r];
        outp[((size_t)bt*1024 + q0 + q)*1152 + hh*72 + dh] = __float2bfloat16(v);
      }
    }
  }
}

extern "C" void kernel_launch(void* const* d_in, const int* in_sizes, int n_in,
                              void* d_out, int out_size, void* d_ws, size_t ws_size,
                              hipStream_t stream)
{
  (void)in_sizes; (void)n_in; (void)out_size; (void)ws_size;
  const float* images = (const float*)d_in[0];
  const float* conv_w = (const float*)d_in[1];
  const float* conv_b = (const float*)d_in[2];
  const float* pos_emb= (const float*)d_in[3];
  const float* ln1_g  = (const float*)d_in[4];
  const float* ln1_b  = (const float*)d_in[5];
  const float* Wq     = (const float*)d_in[6];
  const float* bq     = (const float*)d_in[7];
  const float* Wk     = (const float*)d_in[8];
  const float* bk     = (const float*)d_in[9];
  const float* Wv     = (const float*)d_in[10];
  const float* bv     = (const float*)d_in[11];
  const float* Wo     = (const float*)d_in[12];
  const float* bo     = (const float*)d_in[13];
  const float* ln2_g  = (const float*)d_in[14];
  const float* ln2_b  = (const float*)d_in[15];
  const float* W1     = (const float*)d_in[16];
  const float* b1     = (const float*)d_in[17];
  const float* W2     = (const float*)d_in[18];
  const float* b2     = (const float*)d_in[19];
  const float* lnf_g  = (const float*)d_in[20];
  const float* lnf_b  = (const float*)d_in[21];

  char* p = (char*)d_ws;
  auto take = [&](size_t nbytes)->char*{ char* q = p; p += (nbytes + 255) & ~(size_t)255; return q; };
  float* xw   = (float*)take(4096ull*1152*4);
  bf16* hbuf  = (bf16*) take(4096ull*1152*2);
  bf16* h1    = (bf16*) take(4096ull*4352*2);
  bf16* qkvr  = h1;
  bf16* vbuf  = (bf16*) take(64ull*80*1024*2);
  bf16* imcol = vbuf;
  bf16* aout  = (bf16*) take(4096ull*1152*2);
  bf16* WqkvT = (bf16*) take(3456ull*1152*2);
  bf16* WoT   = (bf16*) take(1152ull*1152*2);
  bf16* W1T   = (bf16*) take(4352ull*1152*2);
  bf16* cwT   = W1T;
  bf16* W2T   = (bf16*) take(1152ull*4352*2);
  bf16* Ppart = (bf16*) take(4ull*4096*1152*2);  // bf16 split-K partials (max ks=4)
  float* bqkv = (float*)take(3456*4);
  float* b1p  = (float*)take(4352*4);
  float4* zbuf= (float4*)take(256);

  const float qscale = 1.4426950408889634f / sqrtf(72.0f);

  im2col_kernel<<<9728, 256, 0, stream>>>(images, imcol);
  transpose_cvt<<<dim3(36,19), 256, 0, stream>>>(conv_w, cwT, 588, 1152, 608, 1152);
  gemm_bf16<4><<<dim3(9,32,2), 256, 0, stream>>>(imcol, cwT, conv_b, Ppart, 1152, 608, 320, 0.f);

  for (int l=0;l<4;l++){
    transpose_cvt<<<dim3(36,36), 256, 0, stream>>>(Wq + (size_t)l*1152*1152, WqkvT,                1152,1152,1152,1152);
    transpose_cvt<<<dim3(36,36), 256, 0, stream>>>(Wk + (size_t)l*1152*1152, WqkvT + 1152ull*1152, 1152,1152,1152,1152);
    transpose_cvt<<<dim3(36,36), 256, 0, stream>>>(Wv + (size_t)l*1152*1152, WqkvT + 2304ull*1152, 1152,1152,1152,1152);
    transpose_cvt<<<dim3(36,36), 256, 0, stream>>>(Wo + (size_t)l*1152*1152, WoT, 1152,1152,1152,1152);
    transpose_cvt<<<dim3(136,36),256, 0, stream>>>(W1 + (size_t)l*1152*4304, W1T, 1152,4304,1152,4352);
    transpose_cvt<<<dim3(36,136),256, 0, stream>>>(W2 + (size_t)l*4304*1152, W2T, 4304,1152,4352,1152);
    pack_biases<<<17,256,0,stream>>>(bq,bk,bv,b1,l,bqkv,b1p,zbuf);

    if (l==0)
      ln_red<0,1><<<1024,256,0,stream>>>(pos_emb, 1023u, Ppart, 2, ln1_g, ln1_b, xw, hbuf);
    else
      ln_red<0,1><<<1024,256,0,stream>>>(xw, 4095u, Ppart, 4, ln1_g + l*1152, ln1_b + l*1152, xw, hbuf);

    gemm_bf16<3><<<dim3(27,32,1),256,0,stream>>>(hbuf, WqkvT, bqkv, qkvr, 3456, 1152, 1152, qscale);
    transpose_v<<<dim3(8,64),256,0,stream>>>(qkvr, vbuf);
    attn_kernel<<<dim3(16,64),256,0,stream>>>(qkvr, vbuf, zbuf, aout);
    gemm_bf16<4><<<dim3(9,32,3),256,0,stream>>>(aout, WoT, bo + l*1152, Ppart, 1152, 1152, 384, 0.f);
    ln_red<0,1><<<1024,256,0,stream>>>(xw, 4095u, Ppart, 3, ln2_g + l*1152, ln2_b + l*1152, xw, hbuf);

    gemm_bf16<1><<<dim3(34,32,1),256,0,stream>>>(hbuf, W1T, b1p, h1, 4352, 1152, 1152, 0.f);
    gemm_bf16<4><<<dim3(9,32,4),256,0,stream>>>(h1, W2T, b2 + l*1152, Ppart, 1152, 4352, 1088, 0.f);
  }
  ln_red<1,0><<<1024,256,0,stream>>>(xw, 4095u, Ppart, 4, lnf_g, lnf_b, nullptr, (float*)d_out);
}